// Round 16
// baseline (1490.849 us; speedup 1.0000x reference)
//
#include <hip/hip_runtime.h>
#include <hip/hip_bf16.h>

// Problem constants
#define Bsz 4
#define Ssz 2048
#define Dsz 2048
#define Hn 16
#define HDsz 128
#define DFF 8192
#define Msz (Bsz*Ssz)   // 8192 rows

typedef __bf16 bf16x8 __attribute__((ext_vector_type(8)));
typedef float  f32x4  __attribute__((ext_vector_type(4)));

enum { FLAG_BIAS=1, FLAG_RELU=2, FLAG_RESID=4, FLAG_F32OUT=8, FLAG_QKV=16 };

#define GLDS16(g, l) __builtin_amdgcn_global_load_lds( \
    (const __attribute__((address_space(1))) unsigned int*)(g), \
    (__attribute__((address_space(3))) unsigned int*)(l), 16, 0, 0)

#define SBAR       asm volatile("s_barrier" ::: "memory")
#define WAIT_VM3   asm volatile("s_waitcnt vmcnt(3)" ::: "memory")
#define WAIT_VM0   asm volatile("s_waitcnt vmcnt(0)" ::: "memory")

// ---------------- tiled transpose + convert to bf16 ----------------
template <typename TIN>
__global__ __launch_bounds__(256) void transpose_cvt(
    const TIN* __restrict__ in, __bf16* __restrict__ out,
    int R, int C, long long inRS, int subB,
    long long strideOuter, long long strideInner, long long outBS)
{
  __shared__ float tile[32][33];
  int bz = blockIdx.z;
  const TIN* inp = in + (size_t)(bz / subB) * strideOuter + (size_t)(bz % subB) * strideInner;
  __bf16* outp = out + (size_t)bz * outBS;
  int tx = threadIdx.x, ty = threadIdx.y;
  int c  = blockIdx.x * 32 + tx;
  int r0 = blockIdx.y * 32;
#pragma unroll
  for (int i = 0; i < 4; ++i) {
    int r = r0 + ty + i * 8;
    tile[ty + i * 8][tx] = (float)inp[(size_t)r * inRS + c];
  }
  __syncthreads();
  int oc  = r0 + tx;
  int or0 = blockIdx.x * 32;
#pragma unroll
  for (int i = 0; i < 4; ++i) {
    int orr = or0 + ty + i * 8;
    outp[(size_t)orr * R + oc] = (__bf16)tile[tx][ty + i * 8];
  }
}

// ---------------- RMSNorm: fp32 in -> bf16 out ----------------
__global__ __launch_bounds__(256) void rmsnorm_k(
    const float* __restrict__ x, const float* __restrict__ g, __bf16* __restrict__ out)
{
  int row = blockIdx.x, tid = threadIdx.x;
  const float4* xr = (const float4*)(x + (size_t)row * Dsz);
  float4 v0 = xr[tid*2], v1 = xr[tid*2+1];
  float ss = v0.x*v0.x + v0.y*v0.y + v0.z*v0.z + v0.w*v0.w
           + v1.x*v1.x + v1.y*v1.y + v1.z*v1.z + v1.w*v1.w;
#pragma unroll
  for (int off = 32; off > 0; off >>= 1) ss += __shfl_down(ss, off);
  __shared__ float wsum[4];
  __shared__ float sc;
  if ((tid & 63) == 0) wsum[tid >> 6] = ss;
  __syncthreads();
  if (tid == 0) {
    float t = wsum[0] + wsum[1] + wsum[2] + wsum[3];
    sc = rsqrtf(t * (1.0f / (float)Dsz) + 1e-8f);
  }
  __syncthreads();
  float s = sc;
  const float4* gr = (const float4*)g;
  float4 g0 = gr[tid*2], g1v = gr[tid*2+1];
  bf16x8 ov;
  ov[0]=(__bf16)(v0.x*s*g0.x);  ov[1]=(__bf16)(v0.y*s*g0.y);
  ov[2]=(__bf16)(v0.z*s*g0.z);  ov[3]=(__bf16)(v0.w*s*g0.w);
  ov[4]=(__bf16)(v1.x*s*g1v.x); ov[5]=(__bf16)(v1.y*s*g1v.y);
  ov[6]=(__bf16)(v1.z*s*g1v.z); ov[7]=(__bf16)(v1.w*s*g1v.w);
  *(bf16x8*)(out + (size_t)row * Dsz + tid * 8) = ov;
}

// ======== GEMM "wide": 1024 thr, 256x256, BK=64 (verified R12) ========
#define WSTG(Xb, Xlds, buf, kh, kst) \
    GLDS16((Xb) + (size_t)wrloc * K + (kst) + (kh)*32 + wsloc, (Xlds) + (buf)*32768 + (kh)*16384 + wwuni)
#define WLDA(kh, mi) (*(const bf16x8*)(AsB + cur*32768 + (kh)*16384 + (wr*64 + (mi)*16 + l15)*64 + psl))
#define WLDB(kh, nj) (*(const bf16x8*)(BsB + cur*32768 + (kh)*16384 + (wc*64 + (nj)*16 + l15)*64 + psl))

__global__ __launch_bounds__(1024) void gemm_w(
    const __bf16* __restrict__ A, const __bf16* __restrict__ B,
    const float* __restrict__ bias, const float* __restrict__ resid,
    void* __restrict__ Cout, void* __restrict__ CoutV,
    int M, int N, int K, int flags)
{
  __shared__ __align__(16) __bf16 As[2*2*256*32];   // 64 KiB
  __shared__ __align__(16) __bf16 Bs[2*2*256*32];   // 64 KiB
  int nwg = gridDim.x;
  int id = blockIdx.x;
  id = (id & 7) * (nwg >> 3) + (id >> 3);           // XCD swizzle (nwg%8==0)
  int ntn = N >> 8;
  int tm = id / ntn, tn = id - tm * ntn;
  int tid = threadIdx.x;
  int lane = tid & 63, w = tid >> 6;                // 16 waves
  int l15 = lane & 15, lg = lane >> 4;
  int wr = w >> 2, wc = w & 3;                      // 4x4 wave grid, 64x64/wave
  const __bf16* Ab = A + (size_t)tm * 256 * K;
  const __bf16* Bb = B + (size_t)tn * 256 * K;
  char* AsB = (char*)As;
  char* BsB = (char*)Bs;
  int wrloc = tid >> 2;                             // staging row 0..255
  int wsloc = ((lane & 3) ^ ((lane >> 3) & 3)) * 8; // inverse-swizzled k-slot (elems)
  int wwuni = w * 1024;                             // wave-uniform LDS base
  int psl  = (lg ^ ((l15 >> 1) & 3)) * 16;          // fragment-read phys slot (bytes)
  f32x4 zero; zero[0]=0.f; zero[1]=0.f; zero[2]=0.f; zero[3]=0.f;
  f32x4 acc[4][4];
#pragma unroll
  for (int i = 0; i < 4; ++i)
#pragma unroll
    for (int j = 0; j < 4; ++j) acc[i][j] = zero;
  int NT = K >> 6;
  WSTG(Ab, AsB, 0, 0, 0);
  WSTG(Ab, AsB, 0, 1, 0);
  WSTG(Bb, BsB, 0, 0, 0);
  WSTG(Bb, BsB, 0, 1, 0);
  WAIT_VM0; SBAR;
  int cur = 0;
  for (int t = 0; t < NT; ++t) {
    int nb = cur ^ 1;
    int kst = (t + 1 < NT) ? ((t + 1) << 6) : 0;
    WSTG(Ab, AsB, nb, 0, kst);
    WSTG(Ab, AsB, nb, 1, kst);
    WSTG(Bb, BsB, nb, 0, kst);
    WSTG(Bb, BsB, nb, 1, kst);
    {
      bf16x8 af[4], bf[4];
      af[0]=WLDA(0,0); af[1]=WLDA(0,1); af[2]=WLDA(0,2); af[3]=WLDA(0,3);
      bf[0]=WLDB(0,0); bf[1]=WLDB(0,1); bf[2]=WLDB(0,2); bf[3]=WLDB(0,3);
#pragma unroll
      for (int mi = 0; mi < 4; ++mi)
#pragma unroll
        for (int nj = 0; nj < 4; ++nj)
          acc[mi][nj] = __builtin_amdgcn_mfma_f32_16x16x32_bf16(af[mi], bf[nj], acc[mi][nj], 0, 0, 0);
    }
    {
      bf16x8 af[4], bf[4];
      af[0]=WLDA(1,0); af[1]=WLDA(1,1); af[2]=WLDA(1,2); af[3]=WLDA(1,3);
      bf[0]=WLDB(1,0); bf[1]=WLDB(1,1); bf[2]=WLDB(1,2); bf[3]=WLDB(1,3);
#pragma unroll
      for (int mi = 0; mi < 4; ++mi)
#pragma unroll
        for (int nj = 0; nj < 4; ++nj)
          acc[mi][nj] = __builtin_amdgcn_mfma_f32_16x16x32_bf16(af[mi], bf[nj], acc[mi][nj], 0, 0, 0);
    }
    WAIT_VM0;
    SBAR;
    cur = nb;
  }
  int cm = tm * 256 + wr * 64;
  int cn = tn * 256 + wc * 64;
  float*  Cf = (float*)Cout;
  __bf16* Cb;
  int Ns = N, cnb = cn;
  if (flags & FLAG_QKV) {
    int which = cn >> 11;   // block-uniform: 0=q, 1=k (contig at Cout), 2=v
    Cb = (which == 2) ? (__bf16*)CoutV
                      : ((__bf16*)Cout + (size_t)which * Msz * 2048);
    Ns = 2048; cnb = cn & 2047;
  } else {
    Cb = (__bf16*)Cout;
  }
#pragma unroll
  for (int m = 0; m < 4; ++m) {
#pragma unroll
    for (int nj = 0; nj < 4; ++nj) {
      int col  = cn  + nj * 16 + l15;
      int colo = cnb + nj * 16 + l15;
      float bv = (flags & FLAG_BIAS) ? bias[col] : 0.0f;
#pragma unroll
      for (int r = 0; r < 4; ++r) {
        int row = cm + m * 16 + 4 * lg + r;
        float v = acc[m][nj][r] + bv;
        if (flags & FLAG_RELU) v = v > 0.f ? v : 0.f;
        size_t idx = (size_t)row * Ns + colo;
        if (flags & FLAG_RESID) v += resid[idx];
        if (flags & FLAG_F32OUT) Cf[idx] = v;
        else                     Cb[idx] = (__bf16)v;
      }
    }
  }
}

// ======== GEMM "narrow": 512 thr, 256x128, BK=32, 2 blocks/CU (verified R13)
#define NSTGA(buf, kst) do { \
    GLDS16(Ab + (size_t)(rloc      ) * K + (kst) + sloc, AsB + (buf)*16384 +        wuni); \
    GLDS16(Ab + (size_t)(rloc + 128) * K + (kst) + sloc, AsB + (buf)*16384 + 8192 + wuni); \
  } while (0)
#define NSTGB(buf, kst) \
    GLDS16(Bb + (size_t)rloc * K + (kst) + sloc, BsB + (buf)*8192 + wuni)
#define NLDA(mi) (*(const bf16x8*)(AsB + cur*16384 + (wr*64 + (mi)*16 + l15)*64 + psl))
#define NLDB(nj) (*(const bf16x8*)(BsB + cur*8192  + (wc*64 + (nj)*16 + l15)*64 + psl))

__global__ __launch_bounds__(512, 4) void gemm_n(
    const __bf16* __restrict__ A, const __bf16* __restrict__ B,
    const float* __restrict__ bias, const float* __restrict__ resid,
    void* __restrict__ Cout, void* __restrict__ CoutV,
    int M, int N, int K, int flags)
{
  __shared__ __align__(16) __bf16 As[3*256*32];   // 48 KiB (3 bufs)
  __shared__ __align__(16) __bf16 Bs[3*128*32];   // 24 KiB (3 bufs)
  int nwg = gridDim.x;
  int id = blockIdx.x;
  id = (id & 7) * (nwg >> 3) + (id >> 3);           // XCD swizzle (nwg%8==0)
  int ntn = N >> 7;
  int tm = id / ntn, tn = id - tm * ntn;
  int tid = threadIdx.x;
  int lane = tid & 63, w = tid >> 6;                // 8 waves
  int l15 = lane & 15, lg = lane >> 4;
  int wr = w >> 1, wc = w & 1;                      // 4x2 wave grid, 64x64/wave
  const __bf16* Ab = A + (size_t)tm * 256 * K;
  const __bf16* Bb = B + (size_t)tn * 128 * K;
  char* AsB = (char*)As;
  char* BsB = (char*)Bs;
  int rloc = tid >> 2;                              // staging row 0..127
  int sloc = ((lane & 3) ^ ((lane >> 3) & 3)) * 8;  // inverse-swizzled k-slot (elems)
  int wuni = w * 1024;                              // wave-uniform LDS base
  int psl  = (lg ^ ((l15 >> 1) & 3)) * 16;          // fragment-read phys slot (bytes)
  f32x4 zero; zero[0]=0.f; zero[1]=0.f; zero[2]=0.f; zero[3]=0.f;
  f32x4 acc[4][4];
#pragma unroll
  for (int i = 0; i < 4; ++i)
#pragma unroll
    for (int j = 0; j < 4; ++j) acc[i][j] = zero;
  int NT = K >> 5;
  NSTGA(0, 0);  NSTGB(0, 0);
  NSTGA(1, 32); NSTGB(1, 32);
  WAIT_VM3; SBAR;
  int cur = 0;
  for (int t = 0; t < NT; ++t) {
    int sb = cur + 2; if (sb >= 3) sb -= 3;
    int kst = (t + 2 < NT) ? ((t + 2) << 5) : 0;    // tail: dummy in-bounds stage
    NSTGA(sb, kst);
    NSTGB(sb, kst);
    bf16x8 af[4], bf[4];
    af[0]=NLDA(0); af[1]=NLDA(1); af[2]=NLDA(2); af[3]=NLDA(3);
    bf[0]=NLDB(0); bf[1]=NLDB(1); bf[2]=NLDB(2); bf[3]=NLDB(3);
#pragma unroll
    for (int mi = 0; mi < 4; ++mi)
#pragma unroll
      for (int nj = 0; nj < 4; ++nj)
        acc[mi][nj] = __builtin_amdgcn_mfma_f32_16x16x32_bf16(af[mi], bf[nj], acc[mi][nj], 0, 0, 0);
    WAIT_VM3;   // certify tile t+1 (issued at t-1)
    SBAR;       // all waves done reading cur; tile t+1 visible block-wide
    cur += 1; if (cur >= 3) cur -= 3;
  }
  WAIT_VM0;  // drain tail dummy stages
  int cm = tm * 256 + wr * 64;
  int cn = tn * 128 + wc * 64;
  float*  Cf = (float*)Cout;
  __bf16* Cb;
  int Ns = N, cnb = cn;
  if (flags & FLAG_QKV) {
    int which = cn >> 11;
    Cb = (which == 2) ? (__bf16*)CoutV
                      : ((__bf16*)Cout + (size_t)which * Msz * 2048);
    Ns = 2048; cnb = cn & 2047;
  } else {
    Cb = (__bf16*)Cout;
  }
#pragma unroll
  for (int m = 0; m < 4; ++m) {
#pragma unroll
    for (int nj = 0; nj < 4; ++nj) {
      int col  = cn  + nj * 16 + l15;
      int colo = cnb + nj * 16 + l15;
      float bv = (flags & FLAG_BIAS) ? bias[col] : 0.0f;
#pragma unroll
      for (int r = 0; r < 4; ++r) {
        int row = cm + m * 16 + 4 * lg + r;
        float v = acc[m][nj][r] + bv;
        if (flags & FLAG_RELU) v = v > 0.f ? v : 0.f;
        size_t idx = (size_t)row * Ns + colo;
        if (flags & FLAG_RESID) v += resid[idx];
        if (flags & FLAG_F32OUT) Cf[idx] = v;
        else                     Cb[idx] = (__bf16)v;
      }
    }
  }
}

// ---------------- causal flash attention v8 ----------------
// v7 (verified R15: ones-column PV-sum, defer-max, setprio) + T14 async
// stage split: tile t+1's K/V global loads are issued into REGISTERS right
// after tile t's post-stage barrier, hiding HBM/L2 latency under compute;
// regs -> LDS at top of iter t+1 (after the barrier certifying all reads of
// tile t done). +16 VGPR (kr[2]+vr[2]); __launch_bounds__(512,4) pins <=128.
__global__ __launch_bounds__(512, 4) void fattn(
    const __bf16* __restrict__ q, const __bf16* __restrict__ k,
    const __bf16* __restrict__ vt, __bf16* __restrict__ o)
{
  __shared__ __align__(16) __bf16 Ks[64*128];     // 16 KiB
  __shared__ __align__(16) __bf16 Vs[144*64];     // 18 KiB (rows 128..143 const)
  __shared__ __align__(16) __bf16 Ps[8][16*72];   // 18 KiB, 144 B rows
  int bx = blockIdx.x, bh = blockIdx.y;
  int b = bh >> 4, h = bh & 15;
  int tid = threadIdx.x, lane = tid & 63, w = tid >> 6;
  int l15 = lane & 15, lg = lane >> 4;
  size_t base = ((size_t)b * Ssz) * Dsz + (size_t)h * HDsz;
  size_t vtb  = (size_t)bh * HDsz * Ssz;
  const float scale = 0.08838834764831845f;  // HD^-0.5
  char* KsB = (char*)Ks;
  char* VsB = (char*)Vs;
  f32x4 zero; zero[0]=0.f; zero[1]=0.f; zero[2]=0.f; zero[3]=0.f;
  // init constant rows 128..143 of Vs: row 128 = 1.0, rows 129..143 = 0
  {
    int idx = tid * 2;                      // 512 thr x 2 elems = 1024 = 16x64
    int rr = 128 + (idx >> 6), cc = idx & 63;
    __bf16 v1 = (rr == 128) ? (__bf16)1.0f : (__bf16)0.0f;
    *(__bf16*)(VsB + rr * 128 + cc * 2)     = v1;
    *(__bf16*)(VsB + rr * 128 + cc * 2 + 2) = v1;
  }

  for (int ph = 0; ph < 2; ++ph) {
    int qt = ph ? bx : (15 - bx);
    int qs = qt * 128;
    int qmin = qs + w * 16;
    bf16x8 qf[4];
    int qrow = qmin + l15;
#pragma unroll
    for (int kk = 0; kk < 4; ++kk)
      qf[kk] = *(const bf16x8*)(q + base + (size_t)qrow * Dsz + kk * 32 + lg * 8);
    f32x4 acc[9];                 // [0..7] = O, [8] = P-row sums (ones column)
#pragma unroll
    for (int i = 0; i < 9; ++i) acc[i] = zero;
    float mr[4];
#pragma unroll
    for (int r = 0; r < 4; ++r) mr[r] = -1e30f;
    int NT = 2 * qt + 2;
    // T14 prologue: issue tile-0 loads into registers
    bf16x8 kr[2], vr[2];
#pragma unroll
    for (int j = 0; j < 2; ++j) {
      int c = tid + j * 512;
      kr[j] = *(const bf16x8*)(k + base + (size_t)(c >> 4) * Dsz + (c & 15) * 8);
      vr[j] = *(const bf16x8*)(vt + vtb + (size_t)(c >> 3) * Ssz + (c & 7) * 8);
    }
    for (int kt = 0; kt < NT; ++kt) {
      int t0 = kt * 64;
      // write staged regs -> LDS (XOR-swizzled; bytes identical to R15)
#pragma unroll
      for (int j = 0; j < 2; ++j) {
        int c = tid + j * 512;
        int tr = c >> 4, hc = c & 15;
        *(bf16x8*)(KsB + ((tr * 256 + hc * 16) ^ ((tr & 7) << 4))) = kr[j];
        int hd = c >> 3, tc = c & 7;
        *(bf16x8*)(VsB + ((hd * 128 + tc * 16) ^ ((hd & 7) << 4))) = vr[j];
      }
      __syncthreads();
      // issue next tile's loads now; latency hides under this tile's compute
      if (kt + 1 < NT) {
        int t1 = t0 + 64;
#pragma unroll
        for (int j = 0; j < 2; ++j) {
          int c = tid + j * 512;
          kr[j] = *(const bf16x8*)(k + base + (size_t)(t1 + (c >> 4)) * Dsz + (c & 15) * 8);
          vr[j] = *(const bf16x8*)(vt + vtb + (size_t)(c >> 3) * Ssz + t1 + (c & 7) * 8);
        }
      }
      bool act = (t0 <= qmin + 15);       // wave-uniform
      if (act) {
        // ---- S = Q K^T
        f32x4 s[4];
#pragma unroll
        for (int cg = 0; cg < 4; ++cg) s[cg] = zero;
        __builtin_amdgcn_s_setprio(1);
#pragma unroll
        for (int kk = 0; kk < 4; ++kk) {
#pragma unroll
          for (int cg = 0; cg < 4; ++cg) {
            int tl = cg * 16 + l15;
            bf16x8 kf = *(const bf16x8*)(KsB + ((tl * 256 + kk * 64 + lg * 16) ^ ((tl & 7) << 4)));
            s[cg] = __builtin_amdgcn_mfma_f32_16x16x32_bf16(qf[kk], kf, s[cg], 0, 0, 0);
          }
        }
        __builtin_amdgcn_s_setprio(0);
        // ---- scale + mask + row maxima; defer-max predicate
        bool nm = (t0 + 63 > qmin);
        float rm[4];
        bool sk = true;
#pragma unroll
        for (int r = 0; r < 4; ++r) {
          int qr = qmin + 4 * lg + r;
          float m0 = -1e30f;
#pragma unroll
          for (int cg = 0; cg < 4; ++cg) {
            float sv = s[cg][r] * scale;
            if (nm && (t0 + cg * 16 + l15) > qr) sv = -1e30f;
            s[cg][r] = sv;
            m0 = fmaxf(m0, sv);
          }
          m0 = fmaxf(m0, __shfl_xor(m0, 1));
          m0 = fmaxf(m0, __shfl_xor(m0, 2));
          m0 = fmaxf(m0, __shfl_xor(m0, 4));
          m0 = fmaxf(m0, __shfl_xor(m0, 8));
          rm[r] = m0;
          sk = sk && (m0 <= mr[r] + 8.0f);
        }
        if (!__all(sk)) {        // rescale only when some row max grew >THR
          f32x4 av;
#pragma unroll
          for (int r = 0; r < 4; ++r) {
            float mn = fmaxf(mr[r], rm[r]);
            av[r] = __expf(mr[r] - mn);
            mr[r] = mn;
          }
#pragma unroll
          for (int hg = 0; hg < 9; ++hg) acc[hg] *= av;
        }
        // ---- P = exp(S - m); write Ps (sum comes free from PV ones-column)
#pragma unroll
        for (int r = 0; r < 4; ++r)
#pragma unroll
          for (int cg = 0; cg < 4; ++cg)
            Ps[w][(4 * lg + r) * 72 + cg * 16 + l15] = (__bf16)__expf(s[cg][r] - mr[r]);
        // ---- O += P V ; acc[8] += P 1  (hg=8 reads the ones row hd=128)
        __builtin_amdgcn_s_setprio(1);
#pragma unroll
        for (int tt = 0; tt < 2; ++tt) {
          bf16x8 pf = *(const bf16x8*)((char*)&Ps[w][0] + l15 * 144 + tt * 64 + lg * 16);
#pragma unroll
          for (int hg = 0; hg < 9; ++hg) {
            int hd = hg * 16 + l15;
            bf16x8 vf = *(const bf16x8*)(VsB + ((hd * 128 + tt * 64 + lg * 16) ^ ((hd & 7) << 4)));
            acc[hg] = __builtin_amdgcn_mfma_f32_16x16x32_bf16(pf, vf, acc[hg], 0, 0, 0);
          }
        }
        __builtin_amdgcn_s_setprio(0);
      }
      __syncthreads();
    }
    // extract row sums from acc[8] (l15==0 lane holds hd=128 column)
    f32x4 inv;
#pragma unroll
    for (int r = 0; r < 4; ++r)
      inv[r] = 1.0f / __shfl(acc[8][r], lane & 48);
#pragma unroll
    for (int hg = 0; hg < 8; ++hg) {
      f32x4 ov = acc[hg] * inv;
#pragma unroll
      for (int r = 0; r < 4; ++r) {
        int qr2 = qmin + 4 * lg + r;
        o[base + (size_t)qr2 * Dsz + hg * 16 + l15] = (__bf16)ov[r];
      }
    }
  }
}

// ---------------- launch ----------------
// Workspace: 20U = 160 MiB. q/k live in d_out (dead before x2 overwrites it).
// FFN chunked x2 over d_ff. GEMM kernel per shape: wide (256^2, 1024thr)
// for QKV; narrow (256x128, 512thr, 2 blocks/CU) for the rest.
extern "C" void kernel_launch(void* const* d_in, const int* in_sizes, int n_in,
                              void* d_out, int out_size, void* d_ws, size_t ws_size,
                              hipStream_t stream)
{
  (void)in_sizes; (void)n_in; (void)out_size; (void)ws_size;
  const float* x  = (const float*)d_in[0];
  const float* wq = (const float*)d_in[1];
  const float* wk = (const float*)d_in[2];
  const float* wv = (const float*)d_in[3];
  const float* wo = (const float*)d_in[4];
  const float* bo = (const float*)d_in[5];
  const float* w1 = (const float*)d_in[6];
  const float* b1 = (const float*)d_in[7];
  const float* w2 = (const float*)d_in[8];
  const float* b2 = (const float*)d_in[9];
  const float* g1 = (const float*)d_in[10];
  const float* g2 = (const float*)d_in[11];
  float* out = (float*)d_out;
  char* ws = (char*)d_ws;

  const size_t U = (size_t)2048 * 2048 * 2;  // 8 MiB
  __bf16* wqT = (__bf16*)(ws);               // [6144][2048] = wq|wk|wv stacked
  __bf16* wkT = (__bf16*)(ws + U);
  __bf16* wvT = (__bf16*)(ws + 2*U);
  __bf16* woT = (__bf16*)(ws + 3*U);
  __bf16* w1T = (__bf16*)(ws + 4*U);         // [8192][2048]
  __bf16* w2T = (__bf16*)(ws + 8*U);         // [2][2048][4096] per-chunk transposed
  __bf16* h1  = (__bf16*)(ws + 12*U);        // [8192][2048]; later vT
  __bf16* vb  = (__bf16*)(ws + 16*U);        // later attn_out
  __bf16* vT    = h1;
  __bf16* attno = vb;
  __bf16* fb    = h1;                        // FFN chunk [8192][4096]
  __bf16* h2    = (__bf16*)(ws);             // overlays dead wqT..woT
  __bf16* qb = (__bf16*)d_out;
  __bf16* kb = qb + (size_t)Msz * Dsz;
  float*  x2 = (float*)d_out;

  dim3 tb(32, 8, 1);
  transpose_cvt<float><<<dim3(4,64,16),  tb, 0, stream>>>(wq, wqT, 2048, 128, 128, 1, (long long)2048*128, 0, (long long)128*2048);
  transpose_cvt<float><<<dim3(4,64,16),  tb, 0, stream>>>(wk, wkT, 2048, 128, 128, 1, (long long)2048*128, 0, (long long)128*2048);
  transpose_cvt<float><<<dim3(4,64,16),  tb, 0, stream>>>(wv, wvT, 2048, 128, 128, 1, (long long)2048*128, 0, (long long)128*2048);
  transpose_cvt<float><<<dim3(64,64,1),  tb, 0, stream>>>(wo, woT, 2048, 2048, 2048, 1, 0, 0, 0);
  transpose_cvt<float><<<dim3(256,64,1), tb, 0, stream>>>(w1, w1T, 2048, 8192, 8192, 1, 0, 0, 0);
  transpose_cvt<float><<<dim3(64,128,2), tb, 0, stream>>>(w2, w2T, 4096, 2048, 2048, 1, (long long)4096*2048, 0, (long long)2048*4096);
  rmsnorm_k<<<8192, 256, 0, stream>>>(x, g1, h1);
  // fused q,k,v = h1 @ [wq|wk|wv]  (q,k -> d_out; v -> vb)
  gemm_w<<<768, 1024, 0, stream>>>(h1, wqT, nullptr, nullptr, qb, vb, Msz, 6144, 2048, FLAG_QKV);
  transpose_cvt<__bf16><<<dim3(4,64,64), tb, 0, stream>>>(vb, vT, 2048, 128, 2048, 16, (long long)2048*2048, 128, (long long)128*2048);
  fattn<<<dim3(8, 64), 512, 0, stream>>>(qb, kb, vT, attno);
  gemm_n<<<512, 512, 0, stream>>>(attno, woT, bo, x, x2, nullptr, Msz, 2048, 2048, FLAG_BIAS | FLAG_RESID | FLAG_F32OUT);
  rmsnorm_k<<<8192, 256, 0, stream>>>(x2, g2, h2);
  for (int c = 0; c < 2; ++c) {
    gemm_n<<<1024, 512, 0, stream>>>(h2, w1T + (size_t)c*4096*2048, b1 + c*4096, nullptr,
                                     fb, nullptr, Msz, 4096, 2048, FLAG_BIAS | FLAG_RELU);
    int fl = FLAG_RESID | FLAG_F32OUT | (c == 0 ? FLAG_BIAS : 0);
    gemm_n<<<512, 512, 0, stream>>>(fb, w2T + (size_t)c*2048*4096, b2, x2,
                                    out, nullptr, Msz, 2048, 4096, fl);
  }
}

// Round 17
// 1256.221 us; speedup vs baseline: 1.1868x; 1.1868x over previous
//
#include <hip/hip_runtime.h>
#include <hip/hip_bf16.h>

// Problem constants
#define Bsz 4
#define Ssz 2048
#define Dsz 2048
#define Hn 16
#define HDsz 128
#define DFF 8192
#define Msz (Bsz*Ssz)   // 8192 rows

typedef __bf16 bf16x8 __attribute__((ext_vector_type(8)));
typedef float  f32x4  __attribute__((ext_vector_type(4)));

enum { FLAG_BIAS=1, FLAG_RELU=2, FLAG_RESID=4, FLAG_F32OUT=8, FLAG_QKV=16 };

#define GLDS16(g, l) __builtin_amdgcn_global_load_lds( \
    (const __attribute__((address_space(1))) unsigned int*)(g), \
    (__attribute__((address_space(3))) unsigned int*)(l), 16, 0, 0)

#define SBAR       asm volatile("s_barrier" ::: "memory")
#define WAIT_VM3   asm volatile("s_waitcnt vmcnt(3)" ::: "memory")
#define WAIT_VM0   asm volatile("s_waitcnt vmcnt(0)" ::: "memory")

// ---------------- tiled transpose + convert to bf16 ----------------
template <typename TIN>
__global__ __launch_bounds__(256) void transpose_cvt(
    const TIN* __restrict__ in, __bf16* __restrict__ out,
    int R, int C, long long inRS, int subB,
    long long strideOuter, long long strideInner, long long outBS)
{
  __shared__ float tile[32][33];
  int bz = blockIdx.z;
  const TIN* inp = in + (size_t)(bz / subB) * strideOuter + (size_t)(bz % subB) * strideInner;
  __bf16* outp = out + (size_t)bz * outBS;
  int tx = threadIdx.x, ty = threadIdx.y;
  int c  = blockIdx.x * 32 + tx;
  int r0 = blockIdx.y * 32;
#pragma unroll
  for (int i = 0; i < 4; ++i) {
    int r = r0 + ty + i * 8;
    tile[ty + i * 8][tx] = (float)inp[(size_t)r * inRS + c];
  }
  __syncthreads();
  int oc  = r0 + tx;
  int or0 = blockIdx.x * 32;
#pragma unroll
  for (int i = 0; i < 4; ++i) {
    int orr = or0 + ty + i * 8;
    outp[(size_t)orr * R + oc] = (__bf16)tile[tx][ty + i * 8];
  }
}

// ---------------- RMSNorm: fp32 in -> bf16 out ----------------
__global__ __launch_bounds__(256) void rmsnorm_k(
    const float* __restrict__ x, const float* __restrict__ g, __bf16* __restrict__ out)
{
  int row = blockIdx.x, tid = threadIdx.x;
  const float4* xr = (const float4*)(x + (size_t)row * Dsz);
  float4 v0 = xr[tid*2], v1 = xr[tid*2+1];
  float ss = v0.x*v0.x + v0.y*v0.y + v0.z*v0.z + v0.w*v0.w
           + v1.x*v1.x + v1.y*v1.y + v1.z*v1.z + v1.w*v1.w;
#pragma unroll
  for (int off = 32; off > 0; off >>= 1) ss += __shfl_down(ss, off);
  __shared__ float wsum[4];
  __shared__ float sc;
  if ((tid & 63) == 0) wsum[tid >> 6] = ss;
  __syncthreads();
  if (tid == 0) {
    float t = wsum[0] + wsum[1] + wsum[2] + wsum[3];
    sc = rsqrtf(t * (1.0f / (float)Dsz) + 1e-8f);
  }
  __syncthreads();
  float s = sc;
  const float4* gr = (const float4*)g;
  float4 g0 = gr[tid*2], g1v = gr[tid*2+1];
  bf16x8 ov;
  ov[0]=(__bf16)(v0.x*s*g0.x);  ov[1]=(__bf16)(v0.y*s*g0.y);
  ov[2]=(__bf16)(v0.z*s*g0.z);  ov[3]=(__bf16)(v0.w*s*g0.w);
  ov[4]=(__bf16)(v1.x*s*g1v.x); ov[5]=(__bf16)(v1.y*s*g1v.y);
  ov[6]=(__bf16)(v1.z*s*g1v.z); ov[7]=(__bf16)(v1.w*s*g1v.w);
  *(bf16x8*)(out + (size_t)row * Dsz + tid * 8) = ov;
}

// ======== GEMM "wide": 1024 thr, 256x256, BK=64 (verified R12) ========
#define WSTG(Xb, Xlds, buf, kh, kst) \
    GLDS16((Xb) + (size_t)wrloc * K + (kst) + (kh)*32 + wsloc, (Xlds) + (buf)*32768 + (kh)*16384 + wwuni)
#define WLDA(kh, mi) (*(const bf16x8*)(AsB + cur*32768 + (kh)*16384 + (wr*64 + (mi)*16 + l15)*64 + psl))
#define WLDB(kh, nj) (*(const bf16x8*)(BsB + cur*32768 + (kh)*16384 + (wc*64 + (nj)*16 + l15)*64 + psl))

__global__ __launch_bounds__(1024) void gemm_w(
    const __bf16* __restrict__ A, const __bf16* __restrict__ B,
    const float* __restrict__ bias, const float* __restrict__ resid,
    void* __restrict__ Cout, void* __restrict__ CoutV,
    int M, int N, int K, int flags)
{
  __shared__ __align__(16) __bf16 As[2*2*256*32];   // 64 KiB
  __shared__ __align__(16) __bf16 Bs[2*2*256*32];   // 64 KiB
  int nwg = gridDim.x;
  int id = blockIdx.x;
  id = (id & 7) * (nwg >> 3) + (id >> 3);           // XCD swizzle (nwg%8==0)
  int ntn = N >> 8;
  int tm = id / ntn, tn = id - tm * ntn;
  int tid = threadIdx.x;
  int lane = tid & 63, w = tid >> 6;                // 16 waves
  int l15 = lane & 15, lg = lane >> 4;
  int wr = w >> 2, wc = w & 3;                      // 4x4 wave grid, 64x64/wave
  const __bf16* Ab = A + (size_t)tm * 256 * K;
  const __bf16* Bb = B + (size_t)tn * 256 * K;
  char* AsB = (char*)As;
  char* BsB = (char*)Bs;
  int wrloc = tid >> 2;                             // staging row 0..255
  int wsloc = ((lane & 3) ^ ((lane >> 3) & 3)) * 8; // inverse-swizzled k-slot (elems)
  int wwuni = w * 1024;                             // wave-uniform LDS base
  int psl  = (lg ^ ((l15 >> 1) & 3)) * 16;          // fragment-read phys slot (bytes)
  f32x4 zero; zero[0]=0.f; zero[1]=0.f; zero[2]=0.f; zero[3]=0.f;
  f32x4 acc[4][4];
#pragma unroll
  for (int i = 0; i < 4; ++i)
#pragma unroll
    for (int j = 0; j < 4; ++j) acc[i][j] = zero;
  int NT = K >> 6;
  WSTG(Ab, AsB, 0, 0, 0);
  WSTG(Ab, AsB, 0, 1, 0);
  WSTG(Bb, BsB, 0, 0, 0);
  WSTG(Bb, BsB, 0, 1, 0);
  WAIT_VM0; SBAR;
  int cur = 0;
  for (int t = 0; t < NT; ++t) {
    int nb = cur ^ 1;
    int kst = (t + 1 < NT) ? ((t + 1) << 6) : 0;
    WSTG(Ab, AsB, nb, 0, kst);
    WSTG(Ab, AsB, nb, 1, kst);
    WSTG(Bb, BsB, nb, 0, kst);
    WSTG(Bb, BsB, nb, 1, kst);
    {
      bf16x8 af[4], bf[4];
      af[0]=WLDA(0,0); af[1]=WLDA(0,1); af[2]=WLDA(0,2); af[3]=WLDA(0,3);
      bf[0]=WLDB(0,0); bf[1]=WLDB(0,1); bf[2]=WLDB(0,2); bf[3]=WLDB(0,3);
#pragma unroll
      for (int mi = 0; mi < 4; ++mi)
#pragma unroll
        for (int nj = 0; nj < 4; ++nj)
          acc[mi][nj] = __builtin_amdgcn_mfma_f32_16x16x32_bf16(af[mi], bf[nj], acc[mi][nj], 0, 0, 0);
    }
    {
      bf16x8 af[4], bf[4];
      af[0]=WLDA(1,0); af[1]=WLDA(1,1); af[2]=WLDA(1,2); af[3]=WLDA(1,3);
      bf[0]=WLDB(1,0); bf[1]=WLDB(1,1); bf[2]=WLDB(1,2); bf[3]=WLDB(1,3);
#pragma unroll
      for (int mi = 0; mi < 4; ++mi)
#pragma unroll
        for (int nj = 0; nj < 4; ++nj)
          acc[mi][nj] = __builtin_amdgcn_mfma_f32_16x16x32_bf16(af[mi], bf[nj], acc[mi][nj], 0, 0, 0);
    }
    WAIT_VM0;
    SBAR;
    cur = nb;
  }
  int cm = tm * 256 + wr * 64;
  int cn = tn * 256 + wc * 64;
  float*  Cf = (float*)Cout;
  __bf16* Cb;
  int Ns = N, cnb = cn;
  if (flags & FLAG_QKV) {
    int which = cn >> 11;   // block-uniform: 0=q, 1=k (contig at Cout), 2=v
    Cb = (which == 2) ? (__bf16*)CoutV
                      : ((__bf16*)Cout + (size_t)which * Msz * 2048);
    Ns = 2048; cnb = cn & 2047;
  } else {
    Cb = (__bf16*)Cout;
  }
#pragma unroll
  for (int m = 0; m < 4; ++m) {
#pragma unroll
    for (int nj = 0; nj < 4; ++nj) {
      int col  = cn  + nj * 16 + l15;
      int colo = cnb + nj * 16 + l15;
      float bv = (flags & FLAG_BIAS) ? bias[col] : 0.0f;
#pragma unroll
      for (int r = 0; r < 4; ++r) {
        int row = cm + m * 16 + 4 * lg + r;
        float v = acc[m][nj][r] + bv;
        if (flags & FLAG_RELU) v = v > 0.f ? v : 0.f;
        size_t idx = (size_t)row * Ns + colo;
        if (flags & FLAG_RESID) v += resid[idx];
        if (flags & FLAG_F32OUT) Cf[idx] = v;
        else                     Cb[idx] = (__bf16)v;
      }
    }
  }
}

// ======== GEMM "narrow": 512 thr, 256x128, BK=32, 2 blocks/CU (verified R13)
#define NSTGA(buf, kst) do { \
    GLDS16(Ab + (size_t)(rloc      ) * K + (kst) + sloc, AsB + (buf)*16384 +        wuni); \
    GLDS16(Ab + (size_t)(rloc + 128) * K + (kst) + sloc, AsB + (buf)*16384 + 8192 + wuni); \
  } while (0)
#define NSTGB(buf, kst) \
    GLDS16(Bb + (size_t)rloc * K + (kst) + sloc, BsB + (buf)*8192 + wuni)
#define NLDA(mi) (*(const bf16x8*)(AsB + cur*16384 + (wr*64 + (mi)*16 + l15)*64 + psl))
#define NLDB(nj) (*(const bf16x8*)(BsB + cur*8192  + (wc*64 + (nj)*16 + l15)*64 + psl))

__global__ __launch_bounds__(512, 4) void gemm_n(
    const __bf16* __restrict__ A, const __bf16* __restrict__ B,
    const float* __restrict__ bias, const float* __restrict__ resid,
    void* __restrict__ Cout, void* __restrict__ CoutV,
    int M, int N, int K, int flags)
{
  __shared__ __align__(16) __bf16 As[3*256*32];   // 48 KiB (3 bufs)
  __shared__ __align__(16) __bf16 Bs[3*128*32];   // 24 KiB (3 bufs)
  int nwg = gridDim.x;
  int id = blockIdx.x;
  id = (id & 7) * (nwg >> 3) + (id >> 3);           // XCD swizzle (nwg%8==0)
  int ntn = N >> 7;
  int tm = id / ntn, tn = id - tm * ntn;
  int tid = threadIdx.x;
  int lane = tid & 63, w = tid >> 6;                // 8 waves
  int l15 = lane & 15, lg = lane >> 4;
  int wr = w >> 1, wc = w & 1;                      // 4x2 wave grid, 64x64/wave
  const __bf16* Ab = A + (size_t)tm * 256 * K;
  const __bf16* Bb = B + (size_t)tn * 128 * K;
  char* AsB = (char*)As;
  char* BsB = (char*)Bs;
  int rloc = tid >> 2;                              // staging row 0..127
  int sloc = ((lane & 3) ^ ((lane >> 3) & 3)) * 8;  // inverse-swizzled k-slot (elems)
  int wuni = w * 1024;                              // wave-uniform LDS base
  int psl  = (lg ^ ((l15 >> 1) & 3)) * 16;          // fragment-read phys slot (bytes)
  f32x4 zero; zero[0]=0.f; zero[1]=0.f; zero[2]=0.f; zero[3]=0.f;
  f32x4 acc[4][4];
#pragma unroll
  for (int i = 0; i < 4; ++i)
#pragma unroll
    for (int j = 0; j < 4; ++j) acc[i][j] = zero;
  int NT = K >> 5;
  NSTGA(0, 0);  NSTGB(0, 0);
  NSTGA(1, 32); NSTGB(1, 32);
  WAIT_VM3; SBAR;
  int cur = 0;
  for (int t = 0; t < NT; ++t) {
    int sb = cur + 2; if (sb >= 3) sb -= 3;
    int kst = (t + 2 < NT) ? ((t + 2) << 5) : 0;    // tail: dummy in-bounds stage
    NSTGA(sb, kst);
    NSTGB(sb, kst);
    bf16x8 af[4], bf[4];
    af[0]=NLDA(0); af[1]=NLDA(1); af[2]=NLDA(2); af[3]=NLDA(3);
    bf[0]=NLDB(0); bf[1]=NLDB(1); bf[2]=NLDB(2); bf[3]=NLDB(3);
#pragma unroll
    for (int mi = 0; mi < 4; ++mi)
#pragma unroll
      for (int nj = 0; nj < 4; ++nj)
        acc[mi][nj] = __builtin_amdgcn_mfma_f32_16x16x32_bf16(af[mi], bf[nj], acc[mi][nj], 0, 0, 0);
    WAIT_VM3;   // certify tile t+1 (issued at t-1)
    SBAR;       // all waves done reading cur; tile t+1 visible block-wide
    cur += 1; if (cur >= 3) cur -= 3;
  }
  WAIT_VM0;  // drain tail dummy stages
  int cm = tm * 256 + wr * 64;
  int cn = tn * 128 + wc * 64;
  float*  Cf = (float*)Cout;
  __bf16* Cb;
  int Ns = N, cnb = cn;
  if (flags & FLAG_QKV) {
    int which = cn >> 11;
    Cb = (which == 2) ? (__bf16*)CoutV
                      : ((__bf16*)Cout + (size_t)which * Msz * 2048);
    Ns = 2048; cnb = cn & 2047;
  } else {
    Cb = (__bf16*)Cout;
  }
#pragma unroll
  for (int m = 0; m < 4; ++m) {
#pragma unroll
    for (int nj = 0; nj < 4; ++nj) {
      int col  = cn  + nj * 16 + l15;
      int colo = cnb + nj * 16 + l15;
      float bv = (flags & FLAG_BIAS) ? bias[col] : 0.0f;
#pragma unroll
      for (int r = 0; r < 4; ++r) {
        int row = cm + m * 16 + 4 * lg + r;
        float v = acc[m][nj][r] + bv;
        if (flags & FLAG_RELU) v = v > 0.f ? v : 0.f;
        size_t idx = (size_t)row * Ns + colo;
        if (flags & FLAG_RESID) v += resid[idx];
        if (flags & FLAG_F32OUT) Cf[idx] = v;
        else                     Cb[idx] = (__bf16)v;
      }
    }
  }
}

// ---------------- causal flash attention v7 (verified R15) ----------------
// ones-column PV-sum: V^T row hd=128 = 1.0 (rows 129-143 zero); acc[8]
// accumulates P-row sums via the PV MFMAs; defer-max (THR=8); setprio.
__global__ __launch_bounds__(512) void fattn(
    const __bf16* __restrict__ q, const __bf16* __restrict__ k,
    const __bf16* __restrict__ vt, __bf16* __restrict__ o)
{
  __shared__ __align__(16) __bf16 Ks[64*128];     // 16 KiB
  __shared__ __align__(16) __bf16 Vs[144*64];     // 18 KiB (rows 128..143 const)
  __shared__ __align__(16) __bf16 Ps[8][16*72];   // 18 KiB, 144 B rows
  int bx = blockIdx.x, bh = blockIdx.y;
  int b = bh >> 4, h = bh & 15;
  int tid = threadIdx.x, lane = tid & 63, w = tid >> 6;
  int l15 = lane & 15, lg = lane >> 4;
  size_t base = ((size_t)b * Ssz) * Dsz + (size_t)h * HDsz;
  size_t vtb  = (size_t)bh * HDsz * Ssz;
  const float scale = 0.08838834764831845f;  // HD^-0.5
  char* KsB = (char*)Ks;
  char* VsB = (char*)Vs;
  f32x4 zero; zero[0]=0.f; zero[1]=0.f; zero[2]=0.f; zero[3]=0.f;
  // init constant rows 128..143 of Vs: row 128 = 1.0, rows 129..143 = 0
  {
    int idx = tid * 2;                      // 512 thr x 2 elems = 1024 = 16x64
    int rr = 128 + (idx >> 6), cc = idx & 63;
    __bf16 v1 = (rr == 128) ? (__bf16)1.0f : (__bf16)0.0f;
    *(__bf16*)(VsB + rr * 128 + cc * 2)     = v1;
    *(__bf16*)(VsB + rr * 128 + cc * 2 + 2) = v1;
  }

  for (int ph = 0; ph < 2; ++ph) {
    int qt = ph ? bx : (15 - bx);
    int qs = qt * 128;
    int qmin = qs + w * 16;
    bf16x8 qf[4];
    int qrow = qmin + l15;
#pragma unroll
    for (int kk = 0; kk < 4; ++kk)
      qf[kk] = *(const bf16x8*)(q + base + (size_t)qrow * Dsz + kk * 32 + lg * 8);
    f32x4 acc[9];                 // [0..7] = O, [8] = P-row sums (ones column)
#pragma unroll
    for (int i = 0; i < 9; ++i) acc[i] = zero;
    float mr[4];
#pragma unroll
    for (int r = 0; r < 4; ++r) mr[r] = -1e30f;
    int NT = 2 * qt + 2;
    for (int kt = 0; kt < NT; ++kt) {
      int t0 = kt * 64;
#pragma unroll
      for (int j = 0; j < 2; ++j) {
        int c = tid + j * 512;
        int tr = c >> 4, hc = c & 15;
        bf16x8 tk = *(const bf16x8*)(k + base + (size_t)(t0 + tr) * Dsz + hc * 8);
        *(bf16x8*)(KsB + ((tr * 256 + hc * 16) ^ ((tr & 7) << 4))) = tk;
        int hd = c >> 3, tc = c & 7;
        bf16x8 tv = *(const bf16x8*)(vt + vtb + (size_t)hd * Ssz + t0 + tc * 8);
        *(bf16x8*)(VsB + ((hd * 128 + tc * 16) ^ ((hd & 7) << 4))) = tv;
      }
      __syncthreads();
      bool act = (t0 <= qmin + 15);       // wave-uniform
      if (act) {
        // ---- S = Q K^T
        f32x4 s[4];
#pragma unroll
        for (int cg = 0; cg < 4; ++cg) s[cg] = zero;
        __builtin_amdgcn_s_setprio(1);
#pragma unroll
        for (int kk = 0; kk < 4; ++kk) {
#pragma unroll
          for (int cg = 0; cg < 4; ++cg) {
            int tl = cg * 16 + l15;
            bf16x8 kf = *(const bf16x8*)(KsB + ((tl * 256 + kk * 64 + lg * 16) ^ ((tl & 7) << 4)));
            s[cg] = __builtin_amdgcn_mfma_f32_16x16x32_bf16(qf[kk], kf, s[cg], 0, 0, 0);
          }
        }
        __builtin_amdgcn_s_setprio(0);
        // ---- scale + mask + row maxima; defer-max predicate
        bool nm = (t0 + 63 > qmin);
        float rm[4];
        bool sk = true;
#pragma unroll
        for (int r = 0; r < 4; ++r) {
          int qr = qmin + 4 * lg + r;
          float m0 = -1e30f;
#pragma unroll
          for (int cg = 0; cg < 4; ++cg) {
            float sv = s[cg][r] * scale;
            if (nm && (t0 + cg * 16 + l15) > qr) sv = -1e30f;
            s[cg][r] = sv;
            m0 = fmaxf(m0, sv);
          }
          m0 = fmaxf(m0, __shfl_xor(m0, 1));
          m0 = fmaxf(m0, __shfl_xor(m0, 2));
          m0 = fmaxf(m0, __shfl_xor(m0, 4));
          m0 = fmaxf(m0, __shfl_xor(m0, 8));
          rm[r] = m0;
          sk = sk && (m0 <= mr[r] + 8.0f);
        }
        if (!__all(sk)) {        // rescale only when some row max grew >THR
          f32x4 av;
#pragma unroll
          for (int r = 0; r < 4; ++r) {
            float mn = fmaxf(mr[r], rm[r]);
            av[r] = __expf(mr[r] - mn);
            mr[r] = mn;
          }
#pragma unroll
          for (int hg = 0; hg < 9; ++hg) acc[hg] *= av;
        }
        // ---- P = exp(S - m); write Ps (sum comes free from PV ones-column)
#pragma unroll
        for (int r = 0; r < 4; ++r)
#pragma unroll
          for (int cg = 0; cg < 4; ++cg)
            Ps[w][(4 * lg + r) * 72 + cg * 16 + l15] = (__bf16)__expf(s[cg][r] - mr[r]);
        // ---- O += P V ; acc[8] += P 1  (hg=8 reads the ones row hd=128)
        __builtin_amdgcn_s_setprio(1);
#pragma unroll
        for (int tt = 0; tt < 2; ++tt) {
          bf16x8 pf = *(const bf16x8*)((char*)&Ps[w][0] + l15 * 144 + tt * 64 + lg * 16);
#pragma unroll
          for (int hg = 0; hg < 9; ++hg) {
            int hd = hg * 16 + l15;
            bf16x8 vf = *(const bf16x8*)(VsB + ((hd * 128 + tt * 64 + lg * 16) ^ ((hd & 7) << 4)));
            acc[hg] = __builtin_amdgcn_mfma_f32_16x16x32_bf16(pf, vf, acc[hg], 0, 0, 0);
          }
        }
        __builtin_amdgcn_s_setprio(0);
      }
      __syncthreads();
    }
    // extract row sums from acc[8] (l15==0 lane holds hd=128 column)
    f32x4 inv;
#pragma unroll
    for (int r = 0; r < 4; ++r)
      inv[r] = 1.0f / __shfl(acc[8][r], lane & 48);
#pragma unroll
    for (int hg = 0; hg < 8; ++hg) {
      f32x4 ov = acc[hg] * inv;
#pragma unroll
      for (int r = 0; r < 4; ++r) {
        int qr2 = qmin + 4 * lg + r;
        o[base + (size_t)qr2 * Dsz + hg * 16 + l15] = (__bf16)ov[r];
      }
    }
  }
}

// ---------------- launch ----------------
// Workspace: 20U = 160 MiB. q/k live in d_out (dead before x2 overwrites it).
// FFN chunked x2 over d_ff. GEMM kernel per shape: wide (256^2, 1024thr)
// for QKV; narrow (256x128, 512thr, 2 blocks/CU) for the rest.
extern "C" void kernel_launch(void* const* d_in, const int* in_sizes, int n_in,
                              void* d_out, int out_size, void* d_ws, size_t ws_size,
                              hipStream_t stream)
{
  (void)in_sizes; (void)n_in; (void)out_size; (void)ws_size;
  const float* x  = (const float*)d_in[0];
  const float* wq = (const float*)d_in[1];
  const float* wk = (const float*)d_in[2];
  const float* wv = (const float*)d_in[3];
  const float* wo = (const float*)d_in[4];
  const float* bo = (const float*)d_in[5];
  const float* w1 = (const float*)d_in[6];
  const float* b1 = (const float*)d_in[7];
  const float* w2 = (const float*)d_in[8];
  const float* b2 = (const float*)d_in[9];
  const float* g1 = (const float*)d_in[10];
  const float* g2 = (const float*)d_in[11];
  float* out = (float*)d_out;
  char* ws = (char*)d_ws;

  const size_t U = (size_t)2048 * 2048 * 2;  // 8 MiB
  __bf16* wqT = (__bf16*)(ws);               // [6144][2048] = wq|wk|wv stacked
  __bf16* wkT = (__bf16*)(ws + U);
  __bf16* wvT = (__bf16*)(ws + 2*U);
  __bf16* woT = (__bf16*)(ws + 3*U);
  __bf16* w1T = (__bf16*)(ws + 4*U);         // [8192][2048]
  __bf16* w2T = (__bf16*)(ws + 8*U);         // [2][2048][4096] per-chunk transposed
  __bf16* h1  = (__bf16*)(ws + 12*U);        // [8192][2048]; later vT
  __bf16* vb  = (__bf16*)(ws + 16*U);        // later attn_out
  __bf16* vT    = h1;
  __bf16* attno = vb;
  __bf16* fb    = h1;                        // FFN chunk [8192][4096]
  __bf16* h2    = (__bf16*)(ws);             // overlays dead wqT..woT
  __bf16* qb = (__bf16*)d_out;
  __bf16* kb = qb + (size_t)Msz * Dsz;
  float*  x2 = (float*)d_out;

  dim3 tb(32, 8, 1);
  transpose_cvt<float><<<dim3(4,64,16),  tb, 0, stream>>>(wq, wqT, 2048, 128, 128, 1, (long long)2048*128, 0, (long long)128*2048);
  transpose_cvt<float><<<dim3(4,64,16),  tb, 0, stream>>>(wk, wkT, 2048, 128, 128, 1, (long long)2048*128, 0, (long long)128*2048);
  transpose_cvt<float><<<dim3(4,64,16),  tb, 0, stream>>>(wv, wvT, 2048, 128, 128, 1, (long long)2048*128, 0, (long long)128*2048);
  transpose_cvt<float><<<dim3(64,64,1),  tb, 0, stream>>>(wo, woT, 2048, 2048, 2048, 1, 0, 0, 0);
  transpose_cvt<float><<<dim3(256,64,1), tb, 0, stream>>>(w1, w1T, 2048, 8192, 8192, 1, 0, 0, 0);
  transpose_cvt<float><<<dim3(64,128,2), tb, 0, stream>>>(w2, w2T, 4096, 2048, 2048, 1, (long long)4096*2048, 0, (long long)2048*4096);
  rmsnorm_k<<<8192, 256, 0, stream>>>(x, g1, h1);
  // fused q,k,v = h1 @ [wq|wk|wv]  (q,k -> d_out; v -> vb)
  gemm_w<<<768, 1024, 0, stream>>>(h1, wqT, nullptr, nullptr, qb, vb, Msz, 6144, 2048, FLAG_QKV);
  transpose_cvt<__bf16><<<dim3(4,64,64), tb, 0, stream>>>(vb, vT, 2048, 128, 2048, 16, (long long)2048*2048, 128, (long long)128*2048);
  fattn<<<dim3(8, 64), 512, 0, stream>>>(qb, kb, vT, attno);
  gemm_n<<<512, 512, 0, stream>>>(attno, woT, bo, x, x2, nullptr, Msz, 2048, 2048, FLAG_BIAS | FLAG_RESID | FLAG_F32OUT);
  rmsnorm_k<<<8192, 256, 0, stream>>>(x2, g2, h2);
  for (int c = 0; c < 2; ++c) {
    gemm_n<<<1024, 512, 0, stream>>>(h2, w1T + (size_t)c*4096*2048, b1 + c*4096, nullptr,
                                     fb, nullptr, Msz, 4096, 2048, FLAG_BIAS | FLAG_RELU);
    int fl = FLAG_RESID | FLAG_F32OUT | (c == 0 ? FLAG_BIAS : 0);
    gemm_n<<<512, 512, 0, stream>>>(fb, w2T + (size_t)c*2048*4096, b2, x2,
                                    out, nullptr, Msz, 2048, 4096, fl);
  }
}